// Round 2
// baseline (4654.340 us; speedup 1.0000x reference)
//
#include <hip/hip_runtime.h>
#include <hip/hip_bf16.h>

// Problem constants
#define B_ 64
#define S_ 128
#define C_ 32
#define D_ 512
#define V_ 20000

typedef __bf16  bf16x8 __attribute__((ext_vector_type(8)));
typedef float   f32x4  __attribute__((ext_vector_type(4)));
typedef __fp16  v2h    __attribute__((ext_vector_type(2)));

// ---- workspace layout (bytes) ----
#define OFF_XBF  0ull          // bf16 x   [8192][512]   8,388,608
#define OFF_UBF  8388608ull    // bf16 U   [2048][512]   2,097,152
#define OFF_WG   10485760ull   // fp16 W_all [2048][512] 2,097,152 (plain row-major)
#define OFF_WD   12582912ull   // fp16 W_d [512][512]      524,288 (plain row-major)
#define OFF_CB   13107200ull   // f32 cb[2048]               8,192
#define OFF_SYNC 13115392ull   // int cnt[1024] @0 ; f32 pooled_red[128] @4096 ; pad to 8192
#define OFF_XB   13123584ull   // fp16 xbuf[2][64][2][512] = 262,144 (h,c exchange, dbl-buffered)
#define OFF_TF   13385728ull   // fp16 tf [8192][512]    8,388,608
#define OFF_UX   21774336ull   // fp16 ux [8192][2048]  33,554,432   -> total ~55.3 MB

// ---------------- zero kernel (sync counters + pooled_red + xbuf) ----------------
__global__ void k_zero(int4* __restrict__ p)
{
    p[blockIdx.x * 256 + threadIdx.x] = int4{0, 0, 0, 0};
}

// ---------------- prep kernels ----------------
__global__ void k_prep_wall(const float* __restrict__ W, _Float16* __restrict__ o)
{
    int i = blockIdx.x * 256 + threadIdx.x;      // 0 .. 1048575
    o[i] = (_Float16)W[i];
}

__global__ void k_prep_wd(const float* __restrict__ W, _Float16* __restrict__ o)
{
    int i = blockIdx.x * 256 + threadIdx.x;      // 0 .. 262143
    o[i] = (_Float16)W[i];
}

__global__ void k_prep_u(const float* __restrict__ U, __hip_bfloat16* __restrict__ o)
{
    int i = blockIdx.x * 256 + threadIdx.x;      // 0 .. 1048575
    o[i] = __float2bfloat16(U[i]);
}

__global__ void k_prep_cb(const float* __restrict__ a, const float* __restrict__ b,
                          float* __restrict__ o)
{
    int i = blockIdx.x * 256 + threadIdx.x;      // 0 .. 2047
    o[i] = a[i] + b[i];
}

// ---------------- embedding gather-sum -> x bf16 ----------------
__global__ void k_embed(const float* __restrict__ emb, const int* __restrict__ seqs,
                        __hip_bfloat16* __restrict__ xbf)
{
    int bs = blockIdx.x;           // b*S + s
    int t  = threadIdx.x;          // 256 threads, 2 floats each
    const int* ip = seqs + (size_t)bs * C_;
    float ax = 0.f, ay = 0.f;
    for (int c = 0; c < C_; c++) {
        int row = ip[c];
        if (row < 0) row = V_;
        const float2 v = *(const float2*)(emb + (size_t)row * D_ + 2 * t);
        ax += v.x; ay += v.y;
    }
    xbf[(size_t)bs * D_ + 2 * t]     = __float2bfloat16(ax);
    xbf[(size_t)bs * D_ + 2 * t + 1] = __float2bfloat16(ay);
}

// ---------------- time feature -> tf fp16 [8192][512] ----------------
__global__ void k_tf(const float* __restrict__ stime, const float* __restrict__ selw,
                     const float* __restrict__ selb, const float* __restrict__ timew,
                     const float* __restrict__ timeb, _Float16* __restrict__ tf)
{
    int bs = blockIdx.x;
    int t  = threadIdx.x;          // 128
    __shared__ float s1[64];
    float tv = stime[bs] * (1.0f / 180.0f);
    if (t < 64) {
        float u = tv * selw[t] + selb[t];
        s1[t] = 1.0f - tanhf(u * u);
    }
    __syncthreads();
    for (int d = t; d < D_; d += 128) {
        float a = timeb[d];
        const float* wr = timew + (size_t)d * 64;
        #pragma unroll 8
        for (int j = 0; j < 64; j++) a += s1[j] * wr[j];
        tf[(size_t)bs * D_ + d] = (_Float16)a;
    }
}

// ---------------- ux GEMM: [8192][512]bf16 x [2048][512]bf16^T -> [8192][2048]fp16 ----
__global__ __launch_bounds__(512) void k_gemm(const __bf16* __restrict__ A,
                                              const __bf16* __restrict__ Bm,
                                              _Float16* __restrict__ Cg)
{
    int lane = threadIdx.x & 63;
    int w    = threadIdx.x >> 6;     // 8 waves
    int wm = w & 3, wn = w >> 2;     // wave tile 32x64
    int q = lane >> 4, r = lane & 15;
    int m0 = blockIdx.y * 128 + wm * 32;
    int n0 = blockIdx.x * 128 + wn * 64;

    const __bf16* pa0 = A  + (size_t)(m0 + r) * 512 + q * 8;
    const __bf16* pa1 = pa0 + (size_t)16 * 512;
    const __bf16* pb  = Bm + (size_t)(n0 + r) * 512 + q * 8;

    f32x4 acc[2][4] = {};
    for (int k = 0; k < 512; k += 32) {
        bf16x8 a0 = *(const bf16x8*)(pa0 + k);
        bf16x8 a1 = *(const bf16x8*)(pa1 + k);
        bf16x8 b0 = *(const bf16x8*)(pb + k);
        bf16x8 b1 = *(const bf16x8*)(pb + (size_t)16 * 512 + k);
        bf16x8 b2 = *(const bf16x8*)(pb + (size_t)32 * 512 + k);
        bf16x8 b3 = *(const bf16x8*)(pb + (size_t)48 * 512 + k);
        acc[0][0] = __builtin_amdgcn_mfma_f32_16x16x32_bf16(a0, b0, acc[0][0], 0, 0, 0);
        acc[0][1] = __builtin_amdgcn_mfma_f32_16x16x32_bf16(a0, b1, acc[0][1], 0, 0, 0);
        acc[0][2] = __builtin_amdgcn_mfma_f32_16x16x32_bf16(a0, b2, acc[0][2], 0, 0, 0);
        acc[0][3] = __builtin_amdgcn_mfma_f32_16x16x32_bf16(a0, b3, acc[0][3], 0, 0, 0);
        acc[1][0] = __builtin_amdgcn_mfma_f32_16x16x32_bf16(a1, b0, acc[1][0], 0, 0, 0);
        acc[1][1] = __builtin_amdgcn_mfma_f32_16x16x32_bf16(a1, b1, acc[1][1], 0, 0, 0);
        acc[1][2] = __builtin_amdgcn_mfma_f32_16x16x32_bf16(a1, b2, acc[1][2], 0, 0, 0);
        acc[1][3] = __builtin_amdgcn_mfma_f32_16x16x32_bf16(a1, b3, acc[1][3], 0, 0, 0);
    }
    for (int am = 0; am < 2; am++)
        for (int bn = 0; bn < 4; bn++) {
            int row = m0 + am * 16 + q * 4;
            int col = n0 + bn * 16 + r;
            _Float16* cp = Cg + (size_t)row * 2048 + col;
            #pragma unroll
            for (int t = 0; t < 4; t++) cp[(size_t)t * 2048] = (_Float16)acc[am][bn][t];
        }
}

// ---------------- recurrence helpers ----------------
__device__ __forceinline__ float dp2(int h, int w, float acc)
{
#if __has_builtin(__builtin_amdgcn_fdot2)
    return __builtin_amdgcn_fdot2(__builtin_bit_cast(v2h, h),
                                  __builtin_bit_cast(v2h, w), acc, false);
#else
    v2h a = __builtin_bit_cast(v2h, h), b = __builtin_bit_cast(v2h, w);
    return acc + (float)a.x * (float)b.x + (float)a.y * (float)b.y;
#endif
}

__device__ __forceinline__ float dot8(int4 h, int4 w, float acc)
{
    acc = dp2(h.x, w.x, acc);
    acc = dp2(h.y, w.y, acc);
    acc = dp2(h.z, w.z, acc);
    acc = dp2(h.w, w.w, acc);
    return acc;
}

// ---------------- recurrence: 8 groups x 32 d-slice blocks, weights in VGPRs ------
// block = (g = bid&7 [group of 8 batches], p = bid>>3 [16-d slice]).
// Each thread holds: gate-row (r=t>>2 of 64, k-quarter q=t&3, 128 k) -> 16 int4 regs,
// plus Wd-row (wr=t>>4 of 16, k-16th wq=t&15, 32 k) -> 4 int4 regs.
// Per step: dot vs h/c of 8 batches, shuffle+LDS reduce, 128 threads do pointwise,
// write h/c slice to global exchange buffer, 32-block device-scope barrier.
__global__ __launch_bounds__(256) void k_rnn2(
    const _Float16* __restrict__ Wg, const _Float16* __restrict__ Wd,
    const float* __restrict__ cbv, const float* __restrict__ wdb,
    const _Float16* __restrict__ ux, const _Float16* __restrict__ tf,
    const float* __restrict__ outw,
    int* __restrict__ cnt, float* __restrict__ pooled_red,
    _Float16* __restrict__ xb)
{
    const int t  = threadIdx.x;
    const int g  = blockIdx.x & 7;     // group (co-XCD if round-robin mapping holds)
    const int p  = blockIdx.x >> 3;    // d-slice 0..31
    const int d0 = p * 16;

    // gate-row task
    const int r   = t >> 2;            // 0..63
    const int q   = t & 3;             // k-quarter (128 k)
    const int gt  = r >> 4;            // gate 0..3 (f,i,o,c)
    const int dlg = r & 15;
    // Wd task
    const int wr  = t >> 4;            // 0..15
    const int wq  = t & 15;            // k-16th (32 k)

    int4 WgR[16];
    {
        const int4* wp = (const int4*)(Wg + ((size_t)(gt * 512 + d0 + dlg)) * 512 + q * 128);
        #pragma unroll
        for (int i = 0; i < 16; i++) WgR[i] = wp[i];
    }
    int4 WdR[4];
    {
        const int4* wp = (const int4*)(Wd + ((size_t)(d0 + wr)) * 512 + wq * 32);
        #pragma unroll
        for (int i = 0; i < 4; i++) WdR[i] = wp[i];
    }

    __shared__ float redg[64][8];
    __shared__ float redd[16][8];

    // pointwise role (t < 128): b = t>>4, dl = t&15
    const int pb  = t >> 4;
    const int pd  = t & 15;
    const int d   = d0 + pd;
    const int bgp = g * 8 + pb;
    float cbf = 0, cbi = 0, cbo = 0, cbc = 0, bdv = 0, ow0 = 0, ow1 = 0;
    if (t < 128) {
        cbf = cbv[d]; cbi = cbv[512 + d]; cbo = cbv[1024 + d]; cbc = cbv[1536 + d];
        bdv = wdb[d];
        ow0 = outw[d]; ow1 = outw[512 + d];
    }
    float c_reg = 0.f, pool = -1e30f;
    int* mycnt = cnt + g * 128;

    for (int s = 0; s < S_; s++) {
        const int sp  = s & 1;
        const int dp_ = sp ^ 1;
        // prefetch u, tf (independent of h — overlaps the dot phase)
        float uf = 0, ui = 0, uo = 0, uc = 0, tfv = 0;
        if (t < 128) {
            const size_t bs = (size_t)bgp * S_ + s;
            const _Float16* up = ux + bs * 2048 + d;
            uf = (float)up[0];    ui = (float)up[512];
            uo = (float)up[1024]; uc = (float)up[1536];
            tfv = (float)tf[bs * 512 + d];
        }
        // dots vs register-resident weights
        float accg[8], accd[8];
        #pragma unroll 2
        for (int b = 0; b < 8; b++) {
            const int bg = g * 8 + b;
            const int4* hp = (const int4*)(xb + ((size_t)(sp * 64 + bg) * 2 + 0) * 512) + q * 16;
            const int4* cp = (const int4*)(xb + ((size_t)(sp * 64 + bg) * 2 + 1) * 512) + wq * 4;
            float a = 0.f;
            #pragma unroll
            for (int i = 0; i < 16; i++) a = dot8(hp[i], WgR[i], a);
            float ad = 0.f;
            #pragma unroll
            for (int i = 0; i < 4; i++) ad = dot8(cp[i], WdR[i], ad);
            accg[b] = a; accd[b] = ad;
        }
        // k-chunk reductions (gate: 4 lanes, Wd: 16 lanes)
        #pragma unroll
        for (int b = 0; b < 8; b++) {
            accg[b] += __shfl_xor(accg[b], 1);
            accg[b] += __shfl_xor(accg[b], 2);
            accd[b] += __shfl_xor(accd[b], 1);
            accd[b] += __shfl_xor(accd[b], 2);
            accd[b] += __shfl_xor(accd[b], 4);
            accd[b] += __shfl_xor(accd[b], 8);
        }
        if (q == 0) {
            #pragma unroll
            for (int b = 0; b < 8; b++) redg[r][b] = accg[b];
        }
        if (wq == 0) {
            #pragma unroll
            for (int b = 0; b < 8; b++) redd[wr][b] = accd[b];
        }
        __syncthreads();
        if (t < 128) {
            float af  = redg[pd][pb],      ai = redg[16 + pd][pb];
            float ao  = redg[32 + pd][pb], ac = redg[48 + pd][pb];
            float ads = redd[pd][pb];
            float gf = 1.f / (1.f + expf(-(af + cbf + uf)));
            float gi = 1.f / (1.f + expf(-(ai + cbi + ui)));
            float go = 1.f / (1.f + expf(-(ao + cbo + uo)));
            float gc = 1.f / (1.f + expf(-(ac + cbc + uc)));
            float cs1  = tanhf(ads + bdv);
            float cadj = c_reg - cs1 + cs1 * tfv;
            float cn   = gf * cadj + gi * gc;
            float hn   = go * tanhf(cn);
            c_reg = cn;
            pool  = fmaxf(pool, hn);
            _Float16* hb = xb + ((size_t)(dp_ * 64 + bgp) * 2 + 0) * 512;
            hb[d]       = (_Float16)hn;   // h slot
            hb[512 + d] = (_Float16)cn;   // c slot
            __threadfence();              // writer waves: make slice device-visible
        }
        if (s != S_ - 1) {
            __syncthreads();              // all writers fenced before arrive
            if (t == 0) {
                __hip_atomic_fetch_add(&mycnt[s], 1, __ATOMIC_RELEASE,
                                       __HIP_MEMORY_SCOPE_AGENT);
                while (__hip_atomic_load(&mycnt[s], __ATOMIC_ACQUIRE,
                                         __HIP_MEMORY_SCOPE_AGENT) < 32)
                    __builtin_amdgcn_s_sleep(1);
            }
            __syncthreads();              // release block; acquire invalidated L1
        } else {
            __syncthreads();
        }
    }

    // pooled epilogue: out partial = sum_dl pooled * out_w[j][d] -> atomic per (b,j)
    if (t < 128) {
        float p0 = pool * ow0, p1 = pool * ow1;
        #pragma unroll
        for (int off = 1; off < 16; off <<= 1) {
            p0 += __shfl_xor(p0, off);
            p1 += __shfl_xor(p1, off);
        }
        if (pd == 0) {
            atomicAdd(&pooled_red[2 * bgp],     p0);
            atomicAdd(&pooled_red[2 * bgp + 1], p1);
        }
    }
}

// ---------------- final output ----------------
__global__ void k_out(const float* __restrict__ pr, const float* __restrict__ outb,
                      float* __restrict__ out)
{
    int i = threadIdx.x;
    if (i < 128) out[i] = pr[i] + outb[i & 1];
}

// ---------------- launch ----------------
extern "C" void kernel_launch(void* const* d_in, const int* in_sizes, int n_in,
                              void* d_out, int out_size, void* d_ws, size_t ws_size,
                              hipStream_t stream)
{
    const float* emb   = (const float*)d_in[0];
    const float* Wall  = (const float*)d_in[1];
    const float* Wallb = (const float*)d_in[2];
    const float* Uall  = (const float*)d_in[3];
    const float* Uallb = (const float*)d_in[4];
    const float* Wdw   = (const float*)d_in[5];
    const float* Wdb   = (const float*)d_in[6];
    const float* selw  = (const float*)d_in[7];
    const float* selb  = (const float*)d_in[8];
    const float* timew = (const float*)d_in[9];
    const float* timeb = (const float*)d_in[10];
    const float* outw  = (const float*)d_in[11];
    const float* outb  = (const float*)d_in[12];
    const float* stime = (const float*)d_in[13];
    const int*   seqs  = (const int*)d_in[14];
    float* out = (float*)d_out;
    char*  ws  = (char*)d_ws;

    __hip_bfloat16* xbf = (__hip_bfloat16*)(ws + OFF_XBF);
    __hip_bfloat16* ubf = (__hip_bfloat16*)(ws + OFF_UBF);
    _Float16* wg   = (_Float16*)(ws + OFF_WG);
    _Float16* wd   = (_Float16*)(ws + OFF_WD);
    float*    cbp  = (float*)(ws + OFF_CB);
    int*      cnt  = (int*)(ws + OFF_SYNC);
    float*    pred = (float*)(ws + OFF_SYNC + 4096);
    _Float16* xb   = (_Float16*)(ws + OFF_XB);
    _Float16* tfp  = (_Float16*)(ws + OFF_TF);
    _Float16* uxp  = (_Float16*)(ws + OFF_UX);

    // zero: cnt (4KB) + pooled_red (512B) + pad (to 8KB) + xbuf (256KB) = 270336 B
    k_zero     <<<66, 256, 0, stream>>>((int4*)(ws + OFF_SYNC));
    k_prep_wall<<<4096, 256, 0, stream>>>(Wall, wg);
    k_prep_wd  <<<1024, 256, 0, stream>>>(Wdw, wd);
    k_prep_u   <<<4096, 256, 0, stream>>>(Uall, ubf);
    k_prep_cb  <<<8,    256, 0, stream>>>(Wallb, Uallb, cbp);
    k_embed    <<<B_ * S_, 256, 0, stream>>>(emb, seqs, xbf);
    k_tf       <<<B_ * S_, 128, 0, stream>>>(stime, selw, selb, timew, timeb, tfp);
    k_gemm     <<<dim3(16, 64), 512, 0, stream>>>((const __bf16*)xbf, (const __bf16*)ubf, uxp);
    k_rnn2     <<<256, 256, 0, stream>>>(wg, wd, cbp, Wdb, uxp, tfp, outw,
                                         cnt, pred, xb);
    k_out      <<<1, 128, 0, stream>>>(pred, outb, out);
}

// Round 4
// 1179.933 us; speedup vs baseline: 3.9446x; 3.9446x over previous
//
#include <hip/hip_runtime.h>
#include <hip/hip_bf16.h>

// Problem constants
#define B_ 64
#define S_ 128
#define C_ 32
#define D_ 512
#define V_ 20000

typedef __bf16  bf16x8 __attribute__((ext_vector_type(8)));
typedef float   f32x4  __attribute__((ext_vector_type(4)));
typedef __fp16  v2h    __attribute__((ext_vector_type(2)));

// ---- workspace layout (bytes) ----
#define OFF_XBF  0ull          // bf16 x   [8192][512]   8,388,608
#define OFF_UBF  8388608ull    // bf16 U   [2048][512]   2,097,152
#define OFF_WG   10485760ull   // fp16 W_all [2048][512] 2,097,152 (plain row-major)
#define OFF_WD   12582912ull   // fp16 W_d [512][512]      524,288 (plain row-major)
#define OFF_CB   13107200ull   // f32 cb[2048]               8,192
#define OFF_SYNC 13115392ull   // int flags[32][8] @0 ; f32 pooled_red[128] @4096 ; pad 8KB
#define OFF_XB   13123584ull   // fp16 xbuf[2][64][2][512] = 262,144 (h,c, dbl-buffered)
#define OFF_TF   13385728ull   // fp16 tf [8192][512]    8,388,608
#define OFF_UX   21774336ull   // fp16 ux [8192][2048]  33,554,432   -> total ~55.3 MB

// ---------------- zero kernel (flags + pooled_red only; xbuf NOT needed) ----------
__global__ void k_zero(int4* __restrict__ p)
{
    p[blockIdx.x * 256 + threadIdx.x] = int4{0, 0, 0, 0};
}

// ---------------- prep kernels ----------------
__global__ void k_prep_wall(const float* __restrict__ W, _Float16* __restrict__ o)
{
    int i = blockIdx.x * 256 + threadIdx.x;      // 0 .. 1048575
    o[i] = (_Float16)W[i];
}

__global__ void k_prep_wd(const float* __restrict__ W, _Float16* __restrict__ o)
{
    int i = blockIdx.x * 256 + threadIdx.x;      // 0 .. 262143
    o[i] = (_Float16)W[i];
}

__global__ void k_prep_u(const float* __restrict__ U, __hip_bfloat16* __restrict__ o)
{
    int i = blockIdx.x * 256 + threadIdx.x;      // 0 .. 1048575
    o[i] = __float2bfloat16(U[i]);
}

__global__ void k_prep_cb(const float* __restrict__ a, const float* __restrict__ b,
                          float* __restrict__ o)
{
    int i = blockIdx.x * 256 + threadIdx.x;      // 0 .. 2047
    o[i] = a[i] + b[i];
}

// ---------------- embedding gather-sum -> x bf16 ----------------
__global__ void k_embed(const float* __restrict__ emb, const int* __restrict__ seqs,
                        __hip_bfloat16* __restrict__ xbf)
{
    int bs = blockIdx.x;           // b*S + s
    int t  = threadIdx.x;          // 256 threads, 2 floats each
    const int* ip = seqs + (size_t)bs * C_;
    float ax = 0.f, ay = 0.f;
    for (int c = 0; c < C_; c++) {
        int row = ip[c];
        if (row < 0) row = V_;
        const float2 v = *(const float2*)(emb + (size_t)row * D_ + 2 * t);
        ax += v.x; ay += v.y;
    }
    xbf[(size_t)bs * D_ + 2 * t]     = __float2bfloat16(ax);
    xbf[(size_t)bs * D_ + 2 * t + 1] = __float2bfloat16(ay);
}

// ---------------- time feature -> tf fp16 [8192][512] ----------------
__global__ void k_tf(const float* __restrict__ stime, const float* __restrict__ selw,
                     const float* __restrict__ selb, const float* __restrict__ timew,
                     const float* __restrict__ timeb, _Float16* __restrict__ tf)
{
    int bs = blockIdx.x;
    int t  = threadIdx.x;          // 128
    __shared__ float s1[64];
    float tv = stime[bs] * (1.0f / 180.0f);
    if (t < 64) {
        float u = tv * selw[t] + selb[t];
        s1[t] = 1.0f - tanhf(u * u);
    }
    __syncthreads();
    for (int d = t; d < D_; d += 128) {
        float a = timeb[d];
        const float* wr = timew + (size_t)d * 64;
        #pragma unroll 8
        for (int j = 0; j < 64; j++) a += s1[j] * wr[j];
        tf[(size_t)bs * D_ + d] = (_Float16)a;
    }
}

// ---------------- ux GEMM: [8192][512]bf16 x [2048][512]bf16^T -> [8192][2048]fp16 ----
__global__ __launch_bounds__(512) void k_gemm(const __bf16* __restrict__ A,
                                              const __bf16* __restrict__ Bm,
                                              _Float16* __restrict__ Cg)
{
    int lane = threadIdx.x & 63;
    int w    = threadIdx.x >> 6;     // 8 waves
    int wm = w & 3, wn = w >> 2;     // wave tile 32x64
    int q = lane >> 4, r = lane & 15;
    int m0 = blockIdx.y * 128 + wm * 32;
    int n0 = blockIdx.x * 128 + wn * 64;

    const __bf16* pa0 = A  + (size_t)(m0 + r) * 512 + q * 8;
    const __bf16* pa1 = pa0 + (size_t)16 * 512;
    const __bf16* pb  = Bm + (size_t)(n0 + r) * 512 + q * 8;

    f32x4 acc[2][4] = {};
    for (int k = 0; k < 512; k += 32) {
        bf16x8 a0 = *(const bf16x8*)(pa0 + k);
        bf16x8 a1 = *(const bf16x8*)(pa1 + k);
        bf16x8 b0 = *(const bf16x8*)(pb + k);
        bf16x8 b1 = *(const bf16x8*)(pb + (size_t)16 * 512 + k);
        bf16x8 b2 = *(const bf16x8*)(pb + (size_t)32 * 512 + k);
        bf16x8 b3 = *(const bf16x8*)(pb + (size_t)48 * 512 + k);
        acc[0][0] = __builtin_amdgcn_mfma_f32_16x16x32_bf16(a0, b0, acc[0][0], 0, 0, 0);
        acc[0][1] = __builtin_amdgcn_mfma_f32_16x16x32_bf16(a0, b1, acc[0][1], 0, 0, 0);
        acc[0][2] = __builtin_amdgcn_mfma_f32_16x16x32_bf16(a0, b2, acc[0][2], 0, 0, 0);
        acc[0][3] = __builtin_amdgcn_mfma_f32_16x16x32_bf16(a0, b3, acc[0][3], 0, 0, 0);
        acc[1][0] = __builtin_amdgcn_mfma_f32_16x16x32_bf16(a1, b0, acc[1][0], 0, 0, 0);
        acc[1][1] = __builtin_amdgcn_mfma_f32_16x16x32_bf16(a1, b1, acc[1][1], 0, 0, 0);
        acc[1][2] = __builtin_amdgcn_mfma_f32_16x16x32_bf16(a1, b2, acc[1][2], 0, 0, 0);
        acc[1][3] = __builtin_amdgcn_mfma_f32_16x16x32_bf16(a1, b3, acc[1][3], 0, 0, 0);
    }
    for (int am = 0; am < 2; am++)
        for (int bn = 0; bn < 4; bn++) {
            int row = m0 + am * 16 + q * 4;
            int col = n0 + bn * 16 + r;
            _Float16* cp = Cg + (size_t)row * 2048 + col;
            #pragma unroll
            for (int t = 0; t < 4; t++) cp[(size_t)t * 2048] = (_Float16)acc[am][bn][t];
        }
}

// ---------------- recurrence helpers ----------------
__device__ __forceinline__ float dp2(int h, int w, float acc)
{
#if __has_builtin(__builtin_amdgcn_fdot2)
    return __builtin_amdgcn_fdot2(__builtin_bit_cast(v2h, h),
                                  __builtin_bit_cast(v2h, w), acc, false);
#else
    v2h a = __builtin_bit_cast(v2h, h), b = __builtin_bit_cast(v2h, w);
    return acc + (float)a.x * (float)b.x + (float)a.y * (float)b.y;
#endif
}

__device__ __forceinline__ float dot8(int4 h, int4 w, float acc)
{
    acc = dp2(h.x, w.x, acc);
    acc = dp2(h.y, w.y, acc);
    acc = dp2(h.z, w.z, acc);
    acc = dp2(h.w, w.w, acc);
    return acc;
}

// ---------------- recurrence: 32 groups x 8 blocks, weights in VGPRs -------------
// Group gid = bid>>3 handles batches {2gid, 2gid+1}. Member m = bid&7 owns d-slice
// d0 = m*64. Thread (rr = t>>3, q8 = t&7): 4 gate rows + Wd row, k-eighth q8 ->
// 160 weight VGPRs. Cross-block h/c + flags via relaxed AGENT atomics (write-
// through to MALL; no fences, no cache-maintenance ops). Flags are per-block
// monotonic step counters; ordering = s_waitcnt vmcnt(0) between data and flag.
// Spin is BOUNDED (safety valve: wrong answer beats a dead container).
__global__ __launch_bounds__(512, 2) void k_rnn4(
    const _Float16* __restrict__ Wg, const _Float16* __restrict__ Wd,
    const float* __restrict__ cbv, const float* __restrict__ wdb,
    const _Float16* __restrict__ ux, const _Float16* __restrict__ tf,
    const float* __restrict__ outw,
    int* __restrict__ flags, float* __restrict__ pooled_red,
    _Float16* __restrict__ xb)
{
    const int t    = threadIdx.x;
    const int gid  = blockIdx.x >> 3;
    const int m    = blockIdx.x & 7;
    const int d0   = m * 64;
    const int b0   = gid * 2;
    const int rr   = t >> 3;           // 0..63 local d
    const int q8   = t & 7;            // k-eighth
    const int lane = t & 63;

    // ---- weights -> VGPRs (chunk order rotated by q8: conflict-free LDS reads) ----
    int4 Wf[8], Wi[8], Wo[8], Wc[8], Wdr[8];
    {
        const int4* p0 = (const int4*)(Wg + ((size_t)(0 * 512 + d0 + rr) * 512 + q8 * 64));
        const int4* p1 = (const int4*)(Wg + ((size_t)(1 * 512 + d0 + rr) * 512 + q8 * 64));
        const int4* p2 = (const int4*)(Wg + ((size_t)(2 * 512 + d0 + rr) * 512 + q8 * 64));
        const int4* p3 = (const int4*)(Wg + ((size_t)(3 * 512 + d0 + rr) * 512 + q8 * 64));
        const int4* pd = (const int4*)(Wd + ((size_t)(d0 + rr) * 512 + q8 * 64));
        #pragma unroll
        for (int i = 0; i < 8; i++) {
            int j = (i + q8) & 7;
            Wf[i] = p0[j]; Wi[i] = p1[j]; Wo[i] = p2[j]; Wc[i] = p3[j]; Wdr[i] = pd[j];
        }
    }

    __shared__ __align__(16) _Float16 hbuf[2][512];
    __shared__ __align__(16) _Float16 cbuf[2][512];
    __shared__ __align__(16) _Float16 ostg[2][2][64];   // [batch][h/c][dl]
    __shared__ float pstg[2][64];

    float c_reg[2] = {0.f, 0.f};
    float pool[2]  = {-1e30f, -1e30f};

    float cbf = 0, cbi = 0, cbo = 0, cbc = 0, bdv = 0;
    if (q8 == 0) {
        int d = d0 + rr;
        cbf = cbv[d]; cbi = cbv[512 + d]; cbo = cbv[1024 + d]; cbc = cbv[1536 + d];
        bdv = wdb[d];
    }
    int* fl = flags + gid * 8;

    for (int s = 0; s < S_; s++) {
        const int sp = s & 1, dpar = sp ^ 1;

        // ux/tf prefetch (independent of h; flies during the poll)
        float uf[2], ui2[2], uo[2], uc[2], tv[2];
        if (q8 == 0) {
            #pragma unroll
            for (int b = 0; b < 2; b++) {
                size_t bs = (size_t)(b0 + b) * S_ + s;
                const _Float16* up = ux + bs * 2048 + (d0 + rr);
                uf[b]  = (float)up[0];    ui2[b] = (float)up[512];
                uo[b]  = (float)up[1024]; uc[b]  = (float)up[1536];
                tv[b]  = (float)tf[bs * 512 + (d0 + rr)];
            }
        }

        // stage H_s, C_s into LDS (zeros at s=0; from MALL otherwise)
        {
            int vec = t >> 7, off = (t & 127) * 4;
            int bb = vec >> 1, hc = vec & 1;
            unsigned long long val = 0ull;
            if (s > 0) {
                // wait for all 8 members to have published step s (bounded spin)
                int tries = 0;
                for (;;) {
                    int v = 0;
                    if (lane < 8)
                        v = __hip_atomic_load(fl + lane, __ATOMIC_RELAXED,
                                              __HIP_MEMORY_SCOPE_AGENT);
                    if (__all(lane >= 8 || v >= s)) break;
                    if (++tries > (1 << 20)) break;   // safety valve, never hit in practice
                    __builtin_amdgcn_s_sleep(1);
                }
                asm volatile("" ::: "memory");        // no hoisting loads above the poll
                unsigned long long* src = (unsigned long long*)
                    (xb + ((size_t)(sp * 64 + b0 + bb) * 2 + hc) * 512 + off);
                val = __hip_atomic_load(src, __ATOMIC_RELAXED,
                                        __HIP_MEMORY_SCOPE_AGENT);
            }
            __syncthreads();             // prior step's LDS consumers are done
            _Float16* dst = (hc ? cbuf[bb] : hbuf[bb]) + off;
            *(unsigned long long*)dst = val;
        }
        __syncthreads();

        // dot phase: register weights x LDS h/c (rotated chunk order)
        float ag[2][4], ad[2];
        #pragma unroll
        for (int b = 0; b < 2; b++) {
            const int4* hp = (const int4*)hbuf[b] + q8 * 8;
            const int4* cp = (const int4*)cbuf[b] + q8 * 8;
            float f_ = 0, i_ = 0, o_ = 0, c_ = 0, d_ = 0;
            #pragma unroll
            for (int i = 0; i < 8; i++) {
                int j = (i + q8) & 7;
                int4 hv = hp[j];
                f_ = dot8(hv, Wf[i], f_);
                i_ = dot8(hv, Wi[i], i_);
                o_ = dot8(hv, Wo[i], o_);
                c_ = dot8(hv, Wc[i], c_);
            }
            #pragma unroll
            for (int i = 0; i < 8; i++) {
                int j = (i + q8) & 7;
                d_ = dot8(cp[j], Wdr[i], d_);
            }
            ag[b][0] = f_; ag[b][1] = i_; ag[b][2] = o_; ag[b][3] = c_; ad[b] = d_;
        }
        // reduce over the 8 k-eighth lanes
        #pragma unroll
        for (int off = 1; off < 8; off <<= 1) {
            #pragma unroll
            for (int b = 0; b < 2; b++) {
                ag[b][0] += __shfl_xor(ag[b][0], off);
                ag[b][1] += __shfl_xor(ag[b][1], off);
                ag[b][2] += __shfl_xor(ag[b][2], off);
                ag[b][3] += __shfl_xor(ag[b][3], off);
                ad[b]    += __shfl_xor(ad[b],    off);
            }
        }

        if (q8 == 0) {
            #pragma unroll
            for (int b = 0; b < 2; b++) {
                float gf = 1.f / (1.f + expf(-(ag[b][0] + cbf + uf[b])));
                float gi = 1.f / (1.f + expf(-(ag[b][1] + cbi + ui2[b])));
                float go = 1.f / (1.f + expf(-(ag[b][2] + cbo + uo[b])));
                float gc = 1.f / (1.f + expf(-(ag[b][3] + cbc + uc[b])));
                float cs1  = tanhf(ad[b] + bdv);
                float cadj = c_reg[b] - cs1 + cs1 * tv[b];
                float cn   = gf * cadj + gi * gc;
                float hn   = go * tanhf(cn);
                c_reg[b] = cn;
                pool[b]  = fmaxf(pool[b], hn);
                ostg[b][0][rr] = (_Float16)hn;
                ostg[b][1][rr] = (_Float16)cn;
            }
        }
        __syncthreads();

        // wave 0 publishes the 512 B slice, then (vmcnt-ordered) the monotonic flag
        if (s != S_ - 1 && t < 64) {
            int b = t >> 5, hc = (t >> 4) & 1, dl4 = (t & 15) * 4;
            unsigned long long val = *(const unsigned long long*)&ostg[b][hc][dl4];
            unsigned long long* dst = (unsigned long long*)
                (xb + ((size_t)(dpar * 64 + b0 + b) * 2 + hc) * 512 + d0 + dl4);
            __hip_atomic_store(dst, val, __ATOMIC_RELAXED, __HIP_MEMORY_SCOPE_AGENT);
            asm volatile("s_waitcnt vmcnt(0)" ::: "memory");   // data at MALL before flag
            if (t == 0)
                __hip_atomic_store(fl + m, s + 1, __ATOMIC_RELAXED,
                                   __HIP_MEMORY_SCOPE_AGENT);
        }
    }

    // pooled epilogue
    if (q8 == 0) { pstg[0][rr] = pool[0]; pstg[1][rr] = pool[1]; }
    __syncthreads();
    if (t < 128) {
        int b = t >> 6, l = t & 63;
        float pv = pstg[b][l];
        int d = d0 + l;
        float p0 = pv * outw[d], p1 = pv * outw[512 + d];
        #pragma unroll
        for (int off = 32; off > 0; off >>= 1) {
            p0 += __shfl_down(p0, off);
            p1 += __shfl_down(p1, off);
        }
        if (l == 0) {
            atomicAdd(&pooled_red[2 * (b0 + b)],     p0);
            atomicAdd(&pooled_red[2 * (b0 + b) + 1], p1);
        }
    }
}

// ---------------- final output ----------------
__global__ void k_out(const float* __restrict__ pr, const float* __restrict__ outb,
                      float* __restrict__ out)
{
    int i = threadIdx.x;
    if (i < 128) out[i] = pr[i] + outb[i & 1];
}

// ---------------- launch ----------------
extern "C" void kernel_launch(void* const* d_in, const int* in_sizes, int n_in,
                              void* d_out, int out_size, void* d_ws, size_t ws_size,
                              hipStream_t stream)
{
    const float* emb   = (const float*)d_in[0];
    const float* Wall  = (const float*)d_in[1];
    const float* Wallb = (const float*)d_in[2];
    const float* Uall  = (const float*)d_in[3];
    const float* Uallb = (const float*)d_in[4];
    const float* Wdw   = (const float*)d_in[5];
    const float* Wdb   = (const float*)d_in[6];
    const float* selw  = (const float*)d_in[7];
    const float* selb  = (const float*)d_in[8];
    const float* timew = (const float*)d_in[9];
    const float* timeb = (const float*)d_in[10];
    const float* outw  = (const float*)d_in[11];
    const float* outb  = (const float*)d_in[12];
    const float* stime = (const float*)d_in[13];
    const int*   seqs  = (const int*)d_in[14];
    float* out = (float*)d_out;
    char*  ws  = (char*)d_ws;

    __hip_bfloat16* xbf = (__hip_bfloat16*)(ws + OFF_XBF);
    __hip_bfloat16* ubf = (__hip_bfloat16*)(ws + OFF_UBF);
    _Float16* wg   = (_Float16*)(ws + OFF_WG);
    _Float16* wd   = (_Float16*)(ws + OFF_WD);
    float*    cbp  = (float*)(ws + OFF_CB);
    int*      flg  = (int*)(ws + OFF_SYNC);
    float*    pred = (float*)(ws + OFF_SYNC + 4096);
    _Float16* xb   = (_Float16*)(ws + OFF_XB);
    _Float16* tfp  = (_Float16*)(ws + OFF_TF);
    _Float16* uxp  = (_Float16*)(ws + OFF_UX);

    // zero: flags (4KB) + pooled_red + pad = 8 KB (xbuf needs no init: s=0 reads none)
    k_zero     <<<2, 256, 0, stream>>>((int4*)(ws + OFF_SYNC));
    k_prep_wall<<<4096, 256, 0, stream>>>(Wall, wg);
    k_prep_wd  <<<1024, 256, 0, stream>>>(Wdw, wd);
    k_prep_u   <<<4096, 256, 0, stream>>>(Uall, ubf);
    k_prep_cb  <<<8,    256, 0, stream>>>(Wallb, Uallb, cbp);
    k_embed    <<<B_ * S_, 256, 0, stream>>>(emb, seqs, xbf);
    k_tf       <<<B_ * S_, 128, 0, stream>>>(stime, selw, selb, timew, timeb, tfp);
    k_gemm     <<<dim3(16, 64), 512, 0, stream>>>((const __bf16*)xbf, (const __bf16*)ubf, uxp);
    k_rnn4     <<<256, 512, 0, stream>>>(wg, wd, cbp, Wdb, uxp, tfp, outw,
                                         flg, pred, xb);
    k_out      <<<1, 128, 0, stream>>>(pred, outb, out);
}